// Round 14
// baseline (127.678 us; speedup 1.0000x reference)
//
#include <hip/hip_runtime.h>
#include <type_traits>
#include <stdint.h>

#define DEV __device__ __forceinline__

typedef float f32x4 __attribute__((ext_vector_type(4)));
typedef short bf16x8 __attribute__((ext_vector_type(8)));
typedef unsigned short u16;
typedef u16 u16x4 __attribute__((ext_vector_type(4)));

static constexpr int BTOT = 65536;
static constexpr int KB   = 64;
static constexpr int NCHT = BTOT / KB;      // 1024 total chunks
static constexpr int NG   = 56;             // true GEMM pairs
static constexpr int NCOLSUM = 45;
static constexpr float INVB = 1.0f / (float)BTOT;

// 32 chunk-windows of 32 chunks (2048 rows). Per window: 7 GEMM blocks
// (one per column, 8 pairs each) + 1 colsum block. grid = 8x32 = 256,
// 1 block/CU. Ping-pong LDS (2x8 slots = 128KB), reg-prefetch, ONE
// barrier per chunk (r7 structure, measured 97us). This round's single
// change: staging writes are fully linear (thread t -> slot u16 offset
// t*4) -> 2-way bank aliasing only (was 8-way, 2.8M conflict cycles).
static constexpr int NWIN  = 32;
static constexpr int CHW   = NCHT / NWIN;   // 32 chunks per GEMM block
static constexpr int NCOLG = 7;
static constexpr int GRID  = 8*NWIN;        // 256
static constexpr int BUFHALF = 8*4096;      // u16s per LDS buffer (8 slots)

struct Col {
  int nslot, np;
  int8_t sexp[8][6];           // slot exps over (s1,y1,s2,y2,x1,x2)
  int8_t pa[8], pb[8];         // pair -> slot indices
  int16_t gout[8];             // pair -> global G slot
  uint8_t ldmask;              // which arrays to load
};

struct Tables {
  int nW, nB, nM, nA, nX;
  int8_t expw[120][7];
  int8_t expb[20][3];
  int8_t expm[56][5];
  int8_t am[35][4];            // 4-var monos (s1,y1,s2,y2), product order
  int8_t xm[10][2];            // 2-var monos, product order
  Col col[NCOLG];
  // combine-kernel term tables
  int8_t wtype[120]; int16_t widx[120]; int8_t wpow[120]; // 0:GEMM 1:colA[o] 2:colX[d]
  int8_t mtype[56];  int16_t midx[56];  int8_t mpow[56];  // 0:GEMM 1:colA[o] 2:colA[d]
  int16_t bcol[20];  int8_t bpow[20];
  int err, gcount;
};

constexpr int aidf(const Tables& t,int a,int b,int c,int d){
  for(int i=0;i<t.nA;i++)
    if(t.am[i][0]==a&&t.am[i][1]==b&&t.am[i][2]==c&&t.am[i][3]==d) return i;
  return -1;
}
constexpr int xidf(const Tables& t,int a,int b){
  for(int i=0;i<t.nX;i++) if(t.xm[i][0]==a&&t.xm[i][1]==b) return i;
  return -1;
}

constexpr Tables makeTables(){
  Tables t{};
  t.err = 0;
  // EXP_W (python product order)
  t.nW=0;
  for(int e0=0;e0<4;e0++)for(int e1=0;e1<4;e1++)for(int e2=0;e2<4;e2++)
  for(int e3=0;e3<4;e3++)for(int e4=0;e4<4;e4++)for(int e5=0;e5<4;e5++)
  for(int e6=0;e6<4;e6++) if(e0+e1+e2+e3+e4+e5+e6<=3){
    t.expw[t.nW][0]=(int8_t)e0; t.expw[t.nW][1]=(int8_t)e1; t.expw[t.nW][2]=(int8_t)e2;
    t.expw[t.nW][3]=(int8_t)e3; t.expw[t.nW][4]=(int8_t)e4; t.expw[t.nW][5]=(int8_t)e5;
    t.expw[t.nW][6]=(int8_t)e6; t.nW++;
  }
  t.nB=0;
  for(int e0=0;e0<4;e0++)for(int e1=0;e1<4;e1++)for(int e2=0;e2<4;e2++)
    if(e0+e1+e2<=3){ t.expb[t.nB][0]=(int8_t)e0; t.expb[t.nB][1]=(int8_t)e1; t.expb[t.nB][2]=(int8_t)e2; t.nB++; }
  t.nM=0;
  for(int e0=0;e0<4;e0++)for(int e1=0;e1<4;e1++)for(int e2=0;e2<4;e2++)
  for(int e3=0;e3<4;e3++)for(int e4=0;e4<4;e4++)
    if(e0+e1+e2+e3+e4<=3){
      t.expm[t.nM][0]=(int8_t)e0; t.expm[t.nM][1]=(int8_t)e1; t.expm[t.nM][2]=(int8_t)e2;
      t.expm[t.nM][3]=(int8_t)e3; t.expm[t.nM][4]=(int8_t)e4; t.nM++;
    }
  t.nA=0;
  for(int a=0;a<4;a++)for(int b=0;b<4;b++)for(int c=0;c<4;c++)for(int d=0;d<4;d++)
    if(a+b+c+d<=3){ t.am[t.nA][0]=(int8_t)a; t.am[t.nA][1]=(int8_t)b; t.am[t.nA][2]=(int8_t)c; t.am[t.nA][3]=(int8_t)d; t.nA++; }
  t.nX=0;
  for(int a=0;a<4;a++)for(int b=0;b<4;b++)
    if(a+b<=3){ t.xm[t.nX][0]=(int8_t)a; t.xm[t.nX][1]=(int8_t)b; t.nX++; }

  int wslot[35][10]; int mslot[10][10];
  for(int i=0;i<35;i++)for(int j=0;j<10;j++) wslot[i][j]=-1;
  for(int i=0;i<10;i++)for(int j=0;j<10;j++) mslot[i][j]=-1;

  int slot=0;

  // --- Col 0: M1 = L(deg1) x R in {y2,y1,y2^2,y1y2} ---
  {
    Col& c=t.col[0]; c.nslot=4; c.np=8;
    int ym[4][2]={{0,1},{1,0},{0,2},{1,1}};   // (y1e,y2e)
    for(int s=0;s<4;s++){ for(int q=0;q<6;q++)c.sexp[s][q]=0;
      c.sexp[s][1]=(int8_t)ym[s][0]; c.sexp[s][3]=(int8_t)ym[s][1]; }
    int p=0;
    for(int L=0;L<2;L++)for(int R=0;R<4;R++){
      c.pa[p]=(int8_t)L; c.pb[p]=(int8_t)R; c.gout[p]=(int16_t)slot;
      mslot[xidf(t,ym[L][0],ym[L][1])][xidf(t,ym[R][0],ym[R][1])]=slot; slot++; p++;
    }
  }
  // --- Col 1: M2 = L(deg1) x y1^2  +  L(deg2) x R(deg1) ---
  {
    Col& c=t.col[1]; c.nslot=5; c.np=8;
    int ym[5][2]={{0,1},{1,0},{0,2},{1,1},{2,0}};
    for(int s=0;s<5;s++){ for(int q=0;q<6;q++)c.sexp[s][q]=0;
      c.sexp[s][1]=(int8_t)ym[s][0]; c.sexp[s][3]=(int8_t)ym[s][1]; }
    int p=0;
    for(int L=0;L<2;L++){
      c.pa[p]=(int8_t)L; c.pb[p]=4; c.gout[p]=(int16_t)slot;
      mslot[xidf(t,ym[L][0],ym[L][1])][xidf(t,2,0)]=slot; slot++; p++;
    }
    for(int i=0;i<3;i++)for(int j=0;j<2;j++){
      c.pa[p]=(int8_t)(2+i); c.pb[p]=(int8_t)j; c.gout[p]=(int16_t)slot;
      mslot[xidf(t,ym[2+i][0],ym[2+i][1])][xidf(t,ym[j][0],ym[j][1])]=slot; slot++; p++;
    }
  }
  // --- Cols 2/4: W1a/W2a = v(deg1) x {x2,x1,x2^2,x1x2} ---
  for(int wc=0; wc<2; wc++){
    Col& c=t.col[2+2*wc]; c.nslot=6; c.np=8;
    int am2[2][2]={{1,0},{0,1}};             // (v0e,v1e)
    int xb[4][2]={{0,1},{1,0},{0,2},{1,1}};  // (x1e,x2e)
    for(int s=0;s<6;s++) for(int q=0;q<6;q++) c.sexp[s][q]=0;
    for(int s=0;s<2;s++){
      c.sexp[s][wc?2:0]=(int8_t)am2[s][0]; c.sexp[s][wc?3:1]=(int8_t)am2[s][1];
    }
    for(int s=0;s<4;s++){ c.sexp[2+s][4]=(int8_t)xb[s][0]; c.sexp[2+s][5]=(int8_t)xb[s][1]; }
    int p=0;
    for(int a=0;a<2;a++)for(int b=0;b<4;b++){
      int amid = wc? aidf(t,0,0,am2[a][0],am2[a][1]) : aidf(t,am2[a][0],am2[a][1],0,0);
      if(amid<0) t.err+=1;
      c.pa[p]=(int8_t)a; c.pb[p]=(int8_t)(2+b); c.gout[p]=(int16_t)slot;
      wslot[amid][xidf(t,xb[b][0],xb[b][1])]=slot; slot++; p++;
    }
  }
  // --- Cols 3/5: W1b/W2b = v(deg1) x x1^2  +  v(deg2) x {x2,x1} ---
  for(int wc=0; wc<2; wc++){
    Col& c=t.col[3+2*wc]; c.nslot=8; c.np=8;
    int am5[5][2]={{1,0},{0,1},{2,0},{1,1},{0,2}};
    int xb[3][2]={{2,0},{0,1},{1,0}};        // slots 5,6,7
    for(int s=0;s<8;s++) for(int q=0;q<6;q++) c.sexp[s][q]=0;
    for(int s=0;s<5;s++){
      c.sexp[s][wc?2:0]=(int8_t)am5[s][0]; c.sexp[s][wc?3:1]=(int8_t)am5[s][1];
    }
    for(int s=0;s<3;s++){ c.sexp[5+s][4]=(int8_t)xb[s][0]; c.sexp[5+s][5]=(int8_t)xb[s][1]; }
    int p=0;
    for(int a=0;a<2;a++){
      int amid = wc? aidf(t,0,0,am5[a][0],am5[a][1]) : aidf(t,am5[a][0],am5[a][1],0,0);
      if(amid<0) t.err+=1;
      c.pa[p]=(int8_t)a; c.pb[p]=5; c.gout[p]=(int16_t)slot;
      wslot[amid][xidf(t,2,0)]=slot; slot++; p++;
    }
    for(int i=0;i<3;i++)for(int j=0;j<2;j++){
      int amid = wc? aidf(t,0,0,am5[2+i][0],am5[2+i][1]) : aidf(t,am5[2+i][0],am5[2+i][1],0,0);
      if(amid<0) t.err+=1;
      c.pa[p]=(int8_t)(2+i); c.pb[p]=(int8_t)(6+j); c.gout[p]=(int16_t)slot;
      wslot[amid][xidf(t,xb[1+j][0],xb[1+j][1])]=slot; slot++; p++;
    }
  }
  // --- Col 6: W3 = mixed-deg2 v x {x2,x1} ---
  {
    Col& c=t.col[6]; c.nslot=6; c.np=8;
    int a4[4][4]={{1,0,1,0},{1,0,0,1},{0,1,1,0},{0,1,0,1}};
    int xb[2][2]={{0,1},{1,0}};
    for(int s=0;s<6;s++) for(int q=0;q<6;q++) c.sexp[s][q]=0;
    for(int s=0;s<4;s++) for(int q=0;q<4;q++) c.sexp[s][q]=(int8_t)a4[s][q];
    for(int s=0;s<2;s++){ c.sexp[4+s][4]=(int8_t)xb[s][0]; c.sexp[4+s][5]=(int8_t)xb[s][1]; }
    int p=0;
    for(int a=0;a<4;a++)for(int b=0;b<2;b++){
      int amid = aidf(t,a4[a][0],a4[a][1],a4[a][2],a4[a][3]);
      if(amid<0) t.err+=1;
      c.pa[p]=(int8_t)a; c.pb[p]=(int8_t)(4+b); c.gout[p]=(int16_t)slot;
      wslot[amid][xidf(t,xb[b][0],xb[b][1])]=slot; slot++; p++;
    }
  }
  t.gcount=slot;
  if(slot!=NG) t.err+=1;

  // ldmask from slot exps
  for(int ci=0; ci<NCOLG; ci++){
    unsigned m=0;
    for(int s=0;s<t.col[ci].nslot;s++)
      for(int v=0;v<6;v++) if(t.col[ci].sexp[s][v]>0) m |= (1u<<v);
    t.col[ci].ldmask=(uint8_t)m;
  }

  // --- combine tables ---
  for(int i=0;i<t.nW;i++){
    const int8_t* e=t.expw[i];
    bool u0=(e[0]==0&&e[3]==0);
    bool v0=(e[1]==0&&e[2]==0&&e[4]==0&&e[5]==0);
    t.wpow[i]=e[6];
    if(u0){ t.wtype[i]=1; t.widx[i]=(int16_t)aidf(t,e[1],e[2],e[4],e[5]); }
    else if(v0){ t.wtype[i]=2; t.widx[i]=(int16_t)xidf(t,e[0],e[3]); }
    else {
      int s=wslot[aidf(t,e[1],e[2],e[4],e[5])][xidf(t,e[0],e[3])];
      if(s<0) t.err+=1;
      t.wtype[i]=0; t.widx[i]=(int16_t)s;
    }
  }
  for(int i=0;i<t.nM;i++){
    const int8_t* e=t.expm[i];
    bool L0=(e[1]==0&&e[3]==0), R0=(e[0]==0&&e[2]==0);
    t.mpow[i]=e[4];
    if(L0){ t.mtype[i]=2; t.midx[i]=(int16_t)aidf(t,0,e[0],0,e[2]); }
    else if(R0){ t.mtype[i]=1; t.midx[i]=(int16_t)aidf(t,0,e[1],0,e[3]); }
    else {
      int s=mslot[xidf(t,e[1],e[3])][xidf(t,e[0],e[2])];
      if(s<0) t.err+=1;
      t.mtype[i]=0; t.midx[i]=(int16_t)s;
    }
  }
  for(int i=0;i<t.nB;i++){
    const int8_t* e=t.expb[i];
    t.bcol[i]=(int16_t)aidf(t,0,e[0],0,e[1]); t.bpow[i]=e[2];
  }
  return t;
}

constexpr Tables TB = makeTables();
static_assert(TB.err==0 && TB.gcount==56, "table build failed");
static_assert(TB.nW==120 && TB.nB==20 && TB.nM==56 && TB.nA==35 && TB.nX==10, "enumeration mismatch");

// ---- helpers ----
template<int N, typename F>
DEV void sunroll(F&& f){
  if constexpr (N > 0){
    sunroll<N-1>(static_cast<F&&>(f));
    f(std::integral_constant<int, N-1>{});
  }
}
template<int E> DEV float ipw(float x){
  if constexpr(E==0) return 1.0f;
  else if constexpr(E==1) return x;
  else if constexpr(E==2) return x*x;
  else return x*x*x;
}
DEV u16 f2bf(float f){
  uint32_t u = __builtin_bit_cast(uint32_t, f);
  u = u + 0x7FFFu + ((u>>16)&1u);
  return (u16)(u>>16);
}

// Fragment-major LDS layout (verified):
// element (b,ch) of a slot at u16 index ((b>>5)*4 + (ch>>4))*512
//   + (((b>>3)&3)*16 + (ch&15))*8 + (b&7)
DEV bf16x8 readFrag(const u16* L, int slot, int sb, int tt, int l){
  return *(const bf16x8*)&L[slot*4096 + ((sb*4 + tt)*64 + l)*8];
}
DEV f32x4 mfma_(bf16x8 a, bf16x8 b, f32x4 c){
  return __builtin_amdgcn_mfma_f32_16x16x32_bf16(a, b, c, 0, 0, 0);
}

// ---- GEMM column: 16 waves, nsplit=2 (each wave: 1 pair, 2 dd-tiles),
// ping-pong LDS, ONE barrier per chunk; MFMA || prefetch || stage co-issue.
// Staging is LINEAR: thread t writes u16x4 at slot*4096 + t*4 (2-way bank
// aliasing = free). Inverse map: P=t>>7, Q=(t>>1)&63, h=t&1 ->
//   ch=(P&3)*16+(Q&15), rows bS..bS+3 with bS=(P>>2)*32+(Q>>4)*8+h*4.
template<int CI>
DEV void colGemm(const float* __restrict__ s1,const float* __restrict__ y1,
                 const float* __restrict__ s2,const float* __restrict__ y2,
                 const float* __restrict__ x1,const float* __restrict__ x2,
                 float* __restrict__ G, u16* lds, int tid, int bi)
{
  constexpr int NS = TB.col[CI].nslot;
  constexpr unsigned LM = TB.col[CI].ldmask;

  const int l = tid&63, w = tid>>6;     // 16 waves
  const int P = tid>>7, Q = (tid>>1)&63, h = tid&1;
  const int chS = (P&3)*16 + (Q&15);
  const int bS  = (P>>2)*32 + (Q>>4)*8 + h*4;
  const int wbase = tid*4;              // linear u16 offset within slot

  int aslot=0,bslot=0,gsl=0,dbase=0;
  sunroll<16>([&](auto W){
    constexpr int ww = decltype(W)::value;
    if(w==ww){
      constexpr int p = ww>>1;
      aslot = TB.col[CI].pa[p];
      bslot = TB.col[CI].pb[p];
      gsl   = TB.col[CI].gout[p];
      dbase = (ww&1)*2;
    }
  });

  const int c0 = bi*CHW, c1 = c0+CHW;
  f32x4 acc[4][2] = {};
  float rw[6][4] = {};

  auto issue = [&](int ck){
    const int b0 = (ck*KB + bS)*64 + chS;
    #pragma unroll
    for(int j=0;j<4;j++){
      const int off = b0 + j*64;
      if constexpr(LM&1u)  rw[0][j]=s1[off];
      if constexpr(LM&2u)  rw[1][j]=y1[off];
      if constexpr(LM&4u)  rw[2][j]=s2[off];
      if constexpr(LM&8u)  rw[3][j]=y2[off];
      if constexpr(LM&16u) rw[4][j]=x1[off];
      if constexpr(LM&32u) rw[5][j]=x2[off];
    }
  };
  auto stage = [&](int buf){
    u16* L = lds + buf*BUFHALF;
    sunroll<NS>([&](auto S){
      constexpr int s = decltype(S)::value;
      u16x4 o4;
      #pragma unroll
      for(int j=0;j<4;j++){
        float v = ipw<TB.col[CI].sexp[s][0]>(rw[0][j])
                * ipw<TB.col[CI].sexp[s][1]>(rw[1][j])
                * ipw<TB.col[CI].sexp[s][2]>(rw[2][j])
                * ipw<TB.col[CI].sexp[s][3]>(rw[3][j])
                * ipw<TB.col[CI].sexp[s][4]>(rw[4][j])
                * ipw<TB.col[CI].sexp[s][5]>(rw[5][j]);
        o4[j]=f2bf(v);
      }
      *(u16x4*)&L[s*4096 + wbase] = o4;
    });
  };

  // prologue: load + stage chunk c0 into buffer 0
  issue(c0);
  stage(0);
  asm volatile("s_waitcnt lgkmcnt(0)" ::: "memory");
  __builtin_amdgcn_s_barrier();
  __builtin_amdgcn_sched_barrier(0);

  for(int k=c0; k<c1; ++k){
    const int t = k - c0;
    const bool notlast = (k+1 < c1);
    if(notlast) issue(k+1);             // global prefetch (latency under MFMA)

    // MFMA on buffer t&1
    const u16* L = lds + (t&1)*BUFHALF;
    #pragma unroll
    for(int sb=0; sb<2; ++sb){
      bf16x8 Af[4];
      #pragma unroll
      for(int o2=0;o2<4;o2++) Af[o2]=readFrag(L,aslot,sb,o2,l);
      #pragma unroll
      for(int dd=0;dd<2;dd++){
        bf16x8 Bf=readFrag(L,bslot,sb,dbase+dd,l);
        #pragma unroll
        for(int o2=0;o2<4;o2++) acc[o2][dd]=mfma_(Af[o2],Bf,acc[o2][dd]);
      }
    }

    if(notlast) stage((t+1)&1);         // stage next chunk into other buffer

    // one barrier per chunk: all LDS ops drained, then sync
    asm volatile("s_waitcnt lgkmcnt(0)" ::: "memory");
    __builtin_amdgcn_s_barrier();
    __builtin_amdgcn_sched_barrier(0);
  }

  // epilogue: atomic partials (C/D layout: col=lane&15, row=(lane>>4)*4+reg)
  const int r0=(l>>4)*4, cc=l&15;
  float* dst = G + gsl*4096;
  #pragma unroll
  for(int o2=0;o2<4;o2++)
    #pragma unroll
    for(int dd=0;dd<2;dd++)
      #pragma unroll
      for(int r=0;r<4;r++)
        atomicAdd(&dst[(o2*16+r0+r)*64 + (dbase+dd)*16+cc], acc[o2][dd][r]);
}

// ---- colsum block (1024 thr): all 45 colsums over 2048 rows ----
DEV void colRed(const float* __restrict__ s1,const float* __restrict__ y1,
                const float* __restrict__ s2,const float* __restrict__ y2,
                const float* __restrict__ x1,const float* __restrict__ x2,
                float* __restrict__ col, float* ldsF, int tid, int bi)
{
  const int ch=tid&63, g16=tid>>6;
  const int base = bi*2048;
  float accv[45];
  sunroll<45>([&](auto K){ accv[decltype(K)::value]=0.f; });
  for(int r=base+g16; r<base+2048; r+=16){
    const int off=r*64+ch;
    const float v0=s1[off],v1=y1[off],v2=s2[off],v3=y2[off],v4=x1[off],v5=x2[off];
    sunroll<35>([&](auto K){
      constexpr int k=decltype(K)::value;
      accv[k] += ipw<TB.am[k][0]>(v0)*ipw<TB.am[k][1]>(v1)*ipw<TB.am[k][2]>(v2)*ipw<TB.am[k][3]>(v3);
    });
    sunroll<10>([&](auto K){
      constexpr int k=decltype(K)::value;
      accv[35+k] += ipw<TB.xm[k][0]>(v4)*ipw<TB.xm[k][1]>(v5);
    });
  }
  sunroll<6>([&](auto RR){
    constexpr int rr=decltype(RR)::value;
    __syncthreads();
    sunroll<8>([&](auto Q){
      constexpr int q=decltype(Q)::value;
      if constexpr(rr*8+q < 45)
        ldsF[(q*16+g16)*64+ch]=accv[rr*8+q];
    });
    __syncthreads();
    {
      const int k=tid>>6, c=tid&63;
      const int idx=rr*8+k;
      if(k<8 && idx<45){
        float s=0.f;
        #pragma unroll
        for(int gg=0; gg<16; gg++) s+=ldsF[(k*16+gg)*64+c];
        atomicAdd(&col[idx*64+c], s);
      }
    }
  });
}

__global__ __launch_bounds__(1024, 4) void k_main(
    const float* __restrict__ x1, const float* __restrict__ s1, const float* __restrict__ y1,
    const float* __restrict__ x2, const float* __restrict__ s2, const float* __restrict__ y2,
    float* __restrict__ G, float* __restrict__ col)
{
  __shared__ u16 lds[2*BUFHALF];   // 128 KiB -> 1 block/CU
  const int tid = threadIdx.x;
  const int u = blockIdx.x >> 5;   // unit
  const int g = blockIdx.x & 31;   // window (XCD = g%8)
  if      (u==0) colGemm<0>(s1,y1,s2,y2,x1,x2,G,lds,tid,g);
  else if (u==1) colGemm<1>(s1,y1,s2,y2,x1,x2,G,lds,tid,g);
  else if (u==2) colGemm<2>(s1,y1,s2,y2,x1,x2,G,lds,tid,g);
  else if (u==3) colGemm<3>(s1,y1,s2,y2,x1,x2,G,lds,tid,g);
  else if (u==4) colGemm<4>(s1,y1,s2,y2,x1,x2,G,lds,tid,g);
  else if (u==5) colGemm<5>(s1,y1,s2,y2,x1,x2,G,lds,tid,g);
  else if (u==6) colGemm<6>(s1,y1,s2,y2,x1,x2,G,lds,tid,g);
  else           colRed(s1,y1,s2,y2,x1,x2,col,(float*)lds,tid,g);
}

__global__ __launch_bounds__(256) void k_combine(
    const float* __restrict__ G, const float* __restrict__ col,
    const float* __restrict__ w, const float* __restrict__ b, const float* __restrict__ m,
    const float* __restrict__ parw, const float* __restrict__ parb, const float* __restrict__ parm,
    float* __restrict__ out)
{
  const int n = blockIdx.x*256 + threadIdx.x;   // 0..4095
  const int o = n>>6, d = n&63;
  const float wv = w[n], mv = m[n];
  const float wp[4] = {1.f, wv, wv*wv, wv*wv*wv};
  const float mp[4] = {1.f, mv, mv*mv, mv*mv*mv};
  float aw=0.f, am=0.f;
  sunroll<120>([&](auto II){
    constexpr int i = decltype(II)::value;
    constexpr int ty = TB.wtype[i];
    constexpr int ix = TB.widx[i];
    constexpr int q  = TB.wpow[i];
    float val;
    if constexpr(ty==0) val = G[ix*4096 + n];
    else if constexpr(ty==1) val = col[ix*64 + o];
    else val = col[(35+ix)*64 + d];
    aw += parw[i] * val * wp[q];
  });
  sunroll<56>([&](auto II){
    constexpr int i = decltype(II)::value;
    constexpr int ty = TB.mtype[i];
    constexpr int ix = TB.midx[i];
    constexpr int q  = TB.mpow[i];
    float val;
    if constexpr(ty==0) val = G[ix*4096 + n];
    else if constexpr(ty==1) val = col[ix*64 + o];
    else val = col[ix*64 + d];
    am += parm[i] * val * mp[q];
  });
  aw *= INVB; am *= INVB;
  if (o==d) am += parm[56];
  out[n] = aw;
  out[4160 + n] = am;
  if (n < 64){
    const float bv = b[n];
    const float bp[4] = {1.f, bv, bv*bv, bv*bv*bv};
    float ab=0.f;
    sunroll<20>([&](auto II){
      constexpr int i = decltype(II)::value;
      constexpr int cix = TB.bcol[i];
      constexpr int q = TB.bpow[i];
      ab += parb[i] * col[cix*64 + n] * bp[q];
    });
    out[4096 + n] = ab * INVB;
  }
}

extern "C" void kernel_launch(void* const* d_in, const int* in_sizes, int n_in,
                              void* d_out, int out_size, void* d_ws, size_t ws_size,
                              hipStream_t stream)
{
  const float* x1=(const float*)d_in[0];
  const float* s1=(const float*)d_in[1];
  const float* y1=(const float*)d_in[2];
  const float* x2=(const float*)d_in[3];
  const float* s2=(const float*)d_in[4];
  const float* y2=(const float*)d_in[5];
  const float* w =(const float*)d_in[6];
  const float* b =(const float*)d_in[7];
  const float* m =(const float*)d_in[8];
  const float* parw=(const float*)d_in[9];
  const float* parb=(const float*)d_in[10];
  const float* parm=(const float*)d_in[11];

  float* G   = (float*)d_ws;
  float* col = G + NG*4096;

  hipMemsetAsync(d_ws, 0, (size_t)(NG*4096 + NCOLSUM*64)*sizeof(float), stream);
  k_main<<<GRID, 1024, 0, stream>>>(x1,s1,y1,x2,s2,y2,G,col);
  k_combine<<<16, 256, 0, stream>>>(G,col,w,b,m,parw,parb,parm,(float*)d_out);
}

// Round 15
// 100.225 us; speedup vs baseline: 1.2739x; 1.2739x over previous
//
#include <hip/hip_runtime.h>
#include <type_traits>
#include <stdint.h>

#define DEV __device__ __forceinline__

typedef float f32x4 __attribute__((ext_vector_type(4)));
typedef short bf16x8 __attribute__((ext_vector_type(8)));
typedef unsigned short u16;
typedef u16 u16x4 __attribute__((ext_vector_type(4)));

static constexpr int BTOT = 65536;
static constexpr int KB   = 64;
static constexpr int NCHT = BTOT / KB;      // 1024 total chunks
static constexpr int NG   = 56;             // true GEMM pairs
static constexpr int NCOLSUM = 45;
static constexpr float INVB = 1.0f / (float)BTOT;

// r7 structure (measured 97us — best of 14 experiments): 32 chunk-windows of
// 32 chunks. Per window: 7 GEMM blocks (one per column, 8 pairs each) + 1
// colsum block. grid = 8x32 = 256 = 1 block/CU. Ping-pong LDS (2x8 slots =
// 128KB), register prefetch of chunk k+1 issued at interval top, ONE barrier
// per chunk. Coalesced scalar loads (quarter-wave covers 16 consecutive ch).
static constexpr int NWIN  = 32;
static constexpr int CHW   = NCHT / NWIN;   // 32 chunks per GEMM block
static constexpr int NCOLG = 7;
static constexpr int GRID  = 8*NWIN;        // 256
static constexpr int BUFHALF = 8*4096;      // u16s per LDS buffer (8 slots)

struct Col {
  int nslot, np;
  int8_t sexp[8][6];           // slot exps over (s1,y1,s2,y2,x1,x2)
  int8_t pa[8], pb[8];         // pair -> slot indices
  int16_t gout[8];             // pair -> global G slot
  uint8_t ldmask;              // which arrays to load
};

struct Tables {
  int nW, nB, nM, nA, nX;
  int8_t expw[120][7];
  int8_t expb[20][3];
  int8_t expm[56][5];
  int8_t am[35][4];            // 4-var monos (s1,y1,s2,y2), product order
  int8_t xm[10][2];            // 2-var monos, product order
  Col col[NCOLG];
  // combine-kernel term tables
  int8_t wtype[120]; int16_t widx[120]; int8_t wpow[120]; // 0:GEMM 1:colA[o] 2:colX[d]
  int8_t mtype[56];  int16_t midx[56];  int8_t mpow[56];  // 0:GEMM 1:colA[o] 2:colA[d]
  int16_t bcol[20];  int8_t bpow[20];
  int err, gcount;
};

constexpr int aidf(const Tables& t,int a,int b,int c,int d){
  for(int i=0;i<t.nA;i++)
    if(t.am[i][0]==a&&t.am[i][1]==b&&t.am[i][2]==c&&t.am[i][3]==d) return i;
  return -1;
}
constexpr int xidf(const Tables& t,int a,int b){
  for(int i=0;i<t.nX;i++) if(t.xm[i][0]==a&&t.xm[i][1]==b) return i;
  return -1;
}

constexpr Tables makeTables(){
  Tables t{};
  t.err = 0;
  // EXP_W (python product order)
  t.nW=0;
  for(int e0=0;e0<4;e0++)for(int e1=0;e1<4;e1++)for(int e2=0;e2<4;e2++)
  for(int e3=0;e3<4;e3++)for(int e4=0;e4<4;e4++)for(int e5=0;e5<4;e5++)
  for(int e6=0;e6<4;e6++) if(e0+e1+e2+e3+e4+e5+e6<=3){
    t.expw[t.nW][0]=(int8_t)e0; t.expw[t.nW][1]=(int8_t)e1; t.expw[t.nW][2]=(int8_t)e2;
    t.expw[t.nW][3]=(int8_t)e3; t.expw[t.nW][4]=(int8_t)e4; t.expw[t.nW][5]=(int8_t)e5;
    t.expw[t.nW][6]=(int8_t)e6; t.nW++;
  }
  t.nB=0;
  for(int e0=0;e0<4;e0++)for(int e1=0;e1<4;e1++)for(int e2=0;e2<4;e2++)
    if(e0+e1+e2<=3){ t.expb[t.nB][0]=(int8_t)e0; t.expb[t.nB][1]=(int8_t)e1; t.expb[t.nB][2]=(int8_t)e2; t.nB++; }
  t.nM=0;
  for(int e0=0;e0<4;e0++)for(int e1=0;e1<4;e1++)for(int e2=0;e2<4;e2++)
  for(int e3=0;e3<4;e3++)for(int e4=0;e4<4;e4++)
    if(e0+e1+e2+e3+e4<=3){
      t.expm[t.nM][0]=(int8_t)e0; t.expm[t.nM][1]=(int8_t)e1; t.expm[t.nM][2]=(int8_t)e2;
      t.expm[t.nM][3]=(int8_t)e3; t.expm[t.nM][4]=(int8_t)e4; t.nM++;
    }
  t.nA=0;
  for(int a=0;a<4;a++)for(int b=0;b<4;b++)for(int c=0;c<4;c++)for(int d=0;d<4;d++)
    if(a+b+c+d<=3){ t.am[t.nA][0]=(int8_t)a; t.am[t.nA][1]=(int8_t)b; t.am[t.nA][2]=(int8_t)c; t.am[t.nA][3]=(int8_t)d; t.nA++; }
  t.nX=0;
  for(int a=0;a<4;a++)for(int b=0;b<4;b++)
    if(a+b<=3){ t.xm[t.nX][0]=(int8_t)a; t.xm[t.nX][1]=(int8_t)b; t.nX++; }

  int wslot[35][10]; int mslot[10][10];
  for(int i=0;i<35;i++)for(int j=0;j<10;j++) wslot[i][j]=-1;
  for(int i=0;i<10;i++)for(int j=0;j<10;j++) mslot[i][j]=-1;

  int slot=0;

  // --- Col 0: M1 = L(deg1) x R in {y2,y1,y2^2,y1y2} ---
  {
    Col& c=t.col[0]; c.nslot=4; c.np=8;
    int ym[4][2]={{0,1},{1,0},{0,2},{1,1}};   // (y1e,y2e)
    for(int s=0;s<4;s++){ for(int q=0;q<6;q++)c.sexp[s][q]=0;
      c.sexp[s][1]=(int8_t)ym[s][0]; c.sexp[s][3]=(int8_t)ym[s][1]; }
    int p=0;
    for(int L=0;L<2;L++)for(int R=0;R<4;R++){
      c.pa[p]=(int8_t)L; c.pb[p]=(int8_t)R; c.gout[p]=(int16_t)slot;
      mslot[xidf(t,ym[L][0],ym[L][1])][xidf(t,ym[R][0],ym[R][1])]=slot; slot++; p++;
    }
  }
  // --- Col 1: M2 = L(deg1) x y1^2  +  L(deg2) x R(deg1) ---
  {
    Col& c=t.col[1]; c.nslot=5; c.np=8;
    int ym[5][2]={{0,1},{1,0},{0,2},{1,1},{2,0}};
    for(int s=0;s<5;s++){ for(int q=0;q<6;q++)c.sexp[s][q]=0;
      c.sexp[s][1]=(int8_t)ym[s][0]; c.sexp[s][3]=(int8_t)ym[s][1]; }
    int p=0;
    for(int L=0;L<2;L++){
      c.pa[p]=(int8_t)L; c.pb[p]=4; c.gout[p]=(int16_t)slot;
      mslot[xidf(t,ym[L][0],ym[L][1])][xidf(t,2,0)]=slot; slot++; p++;
    }
    for(int i=0;i<3;i++)for(int j=0;j<2;j++){
      c.pa[p]=(int8_t)(2+i); c.pb[p]=(int8_t)j; c.gout[p]=(int16_t)slot;
      mslot[xidf(t,ym[2+i][0],ym[2+i][1])][xidf(t,ym[j][0],ym[j][1])]=slot; slot++; p++;
    }
  }
  // --- Cols 2/4: W1a/W2a = v(deg1) x {x2,x1,x2^2,x1x2} ---
  for(int wc=0; wc<2; wc++){
    Col& c=t.col[2+2*wc]; c.nslot=6; c.np=8;
    int am2[2][2]={{1,0},{0,1}};             // (v0e,v1e)
    int xb[4][2]={{0,1},{1,0},{0,2},{1,1}};  // (x1e,x2e)
    for(int s=0;s<6;s++) for(int q=0;q<6;q++) c.sexp[s][q]=0;
    for(int s=0;s<2;s++){
      c.sexp[s][wc?2:0]=(int8_t)am2[s][0]; c.sexp[s][wc?3:1]=(int8_t)am2[s][1];
    }
    for(int s=0;s<4;s++){ c.sexp[2+s][4]=(int8_t)xb[s][0]; c.sexp[2+s][5]=(int8_t)xb[s][1]; }
    int p=0;
    for(int a=0;a<2;a++)for(int b=0;b<4;b++){
      int amid = wc? aidf(t,0,0,am2[a][0],am2[a][1]) : aidf(t,am2[a][0],am2[a][1],0,0);
      if(amid<0) t.err+=1;
      c.pa[p]=(int8_t)a; c.pb[p]=(int8_t)(2+b); c.gout[p]=(int16_t)slot;
      wslot[amid][xidf(t,xb[b][0],xb[b][1])]=slot; slot++; p++;
    }
  }
  // --- Cols 3/5: W1b/W2b = v(deg1) x x1^2  +  v(deg2) x {x2,x1} ---
  for(int wc=0; wc<2; wc++){
    Col& c=t.col[3+2*wc]; c.nslot=8; c.np=8;
    int am5[5][2]={{1,0},{0,1},{2,0},{1,1},{0,2}};
    int xb[3][2]={{2,0},{0,1},{1,0}};        // slots 5,6,7
    for(int s=0;s<8;s++) for(int q=0;q<6;q++) c.sexp[s][q]=0;
    for(int s=0;s<5;s++){
      c.sexp[s][wc?2:0]=(int8_t)am5[s][0]; c.sexp[s][wc?3:1]=(int8_t)am5[s][1];
    }
    for(int s=0;s<3;s++){ c.sexp[5+s][4]=(int8_t)xb[s][0]; c.sexp[5+s][5]=(int8_t)xb[s][1]; }
    int p=0;
    for(int a=0;a<2;a++){
      int amid = wc? aidf(t,0,0,am5[a][0],am5[a][1]) : aidf(t,am5[a][0],am5[a][1],0,0);
      if(amid<0) t.err+=1;
      c.pa[p]=(int8_t)a; c.pb[p]=5; c.gout[p]=(int16_t)slot;
      wslot[amid][xidf(t,2,0)]=slot; slot++; p++;
    }
    for(int i=0;i<3;i++)for(int j=0;j<2;j++){
      int amid = wc? aidf(t,0,0,am5[2+i][0],am5[2+i][1]) : aidf(t,am5[2+i][0],am5[2+i][1],0,0);
      if(amid<0) t.err+=1;
      c.pa[p]=(int8_t)(2+i); c.pb[p]=(int8_t)(6+j); c.gout[p]=(int16_t)slot;
      wslot[amid][xidf(t,xb[1+j][0],xb[1+j][1])]=slot; slot++; p++;
    }
  }
  // --- Col 6: W3 = mixed-deg2 v x {x2,x1} ---
  {
    Col& c=t.col[6]; c.nslot=6; c.np=8;
    int a4[4][4]={{1,0,1,0},{1,0,0,1},{0,1,1,0},{0,1,0,1}};
    int xb[2][2]={{0,1},{1,0}};
    for(int s=0;s<6;s++) for(int q=0;q<6;q++) c.sexp[s][q]=0;
    for(int s=0;s<4;s++) for(int q=0;q<4;q++) c.sexp[s][q]=(int8_t)a4[s][q];
    for(int s=0;s<2;s++){ c.sexp[4+s][4]=(int8_t)xb[s][0]; c.sexp[4+s][5]=(int8_t)xb[s][1]; }
    int p=0;
    for(int a=0;a<4;a++)for(int b=0;b<2;b++){
      int amid = aidf(t,a4[a][0],a4[a][1],a4[a][2],a4[a][3]);
      if(amid<0) t.err+=1;
      c.pa[p]=(int8_t)a; c.pb[p]=(int8_t)(4+b); c.gout[p]=(int16_t)slot;
      wslot[amid][xidf(t,xb[b][0],xb[b][1])]=slot; slot++; p++;
    }
  }
  t.gcount=slot;
  if(slot!=NG) t.err+=1;

  // ldmask from slot exps
  for(int ci=0; ci<NCOLG; ci++){
    unsigned m=0;
    for(int s=0;s<t.col[ci].nslot;s++)
      for(int v=0;v<6;v++) if(t.col[ci].sexp[s][v]>0) m |= (1u<<v);
    t.col[ci].ldmask=(uint8_t)m;
  }

  // --- combine tables ---
  for(int i=0;i<t.nW;i++){
    const int8_t* e=t.expw[i];
    bool u0=(e[0]==0&&e[3]==0);
    bool v0=(e[1]==0&&e[2]==0&&e[4]==0&&e[5]==0);
    t.wpow[i]=e[6];
    if(u0){ t.wtype[i]=1; t.widx[i]=(int16_t)aidf(t,e[1],e[2],e[4],e[5]); }
    else if(v0){ t.wtype[i]=2; t.widx[i]=(int16_t)xidf(t,e[0],e[3]); }
    else {
      int s=wslot[aidf(t,e[1],e[2],e[4],e[5])][xidf(t,e[0],e[3])];
      if(s<0) t.err+=1;
      t.wtype[i]=0; t.widx[i]=(int16_t)s;
    }
  }
  for(int i=0;i<t.nM;i++){
    const int8_t* e=t.expm[i];
    bool L0=(e[1]==0&&e[3]==0), R0=(e[0]==0&&e[2]==0);
    t.mpow[i]=e[4];
    if(L0){ t.mtype[i]=2; t.midx[i]=(int16_t)aidf(t,0,e[0],0,e[2]); }
    else if(R0){ t.mtype[i]=1; t.midx[i]=(int16_t)aidf(t,0,e[1],0,e[3]); }
    else {
      int s=mslot[xidf(t,e[1],e[3])][xidf(t,e[0],e[2])];
      if(s<0) t.err+=1;
      t.mtype[i]=0; t.midx[i]=(int16_t)s;
    }
  }
  for(int i=0;i<t.nB;i++){
    const int8_t* e=t.expb[i];
    t.bcol[i]=(int16_t)aidf(t,0,e[0],0,e[1]); t.bpow[i]=e[2];
  }
  return t;
}

constexpr Tables TB = makeTables();
static_assert(TB.err==0 && TB.gcount==56, "table build failed");
static_assert(TB.nW==120 && TB.nB==20 && TB.nM==56 && TB.nA==35 && TB.nX==10, "enumeration mismatch");

// ---- helpers ----
template<int N, typename F>
DEV void sunroll(F&& f){
  if constexpr (N > 0){
    sunroll<N-1>(static_cast<F&&>(f));
    f(std::integral_constant<int, N-1>{});
  }
}
template<int E> DEV float ipw(float x){
  if constexpr(E==0) return 1.0f;
  else if constexpr(E==1) return x;
  else if constexpr(E==2) return x*x;
  else return x*x*x;
}
DEV u16 f2bf(float f){
  uint32_t u = __builtin_bit_cast(uint32_t, f);
  u = u + 0x7FFFu + ((u>>16)&1u);
  return (u16)(u>>16);
}

// Fragment-major LDS layout (verified):
// element (b,ch) of a slot at u16 index ((b>>5)*4 + (ch>>4))*512
//   + (((b>>3)&3)*16 + (ch&15))*8 + (b&7)
DEV bf16x8 readFrag(const u16* L, int slot, int sb, int tt, int l){
  return *(const bf16x8*)&L[slot*4096 + ((sb*4 + tt)*64 + l)*8];
}
DEV f32x4 mfma_(bf16x8 a, bf16x8 b, f32x4 c){
  return __builtin_amdgcn_mfma_f32_16x16x32_bf16(a, b, c, 0, 0, 0);
}

// ---- GEMM column: 16 waves, nsplit=2 (each wave: 1 pair, 2 dd-tiles),
// ping-pong LDS, ONE barrier per chunk; MFMA || prefetch || stage co-issue ----
template<int CI>
DEV void colGemm(const float* __restrict__ s1,const float* __restrict__ y1,
                 const float* __restrict__ s2,const float* __restrict__ y2,
                 const float* __restrict__ x1,const float* __restrict__ x2,
                 float* __restrict__ G, u16* lds, int tid, int bi)
{
  constexpr int NS = TB.col[CI].nslot;
  constexpr unsigned LM = TB.col[CI].ldmask;

  const int l = tid&63, w = tid>>6;     // 16 waves
  // staging: thread (w,l) owns b = bl..bl+3 at ch; u16x4 write (r7 mapping).
  const int q = (l>>4)&3;
  const int ob = (tid>>6)&3, sub = tid>>8;
  const int ch = ob*16 + (l&15);
  const int bl = sub*16 + q*4;
  const int wbase = ((( (sub>>1)*4 + ob)*64) + ((sub&1)*2 + (q>>1))*16 + (l&15))*8 + (q&1)*4;

  int aslot=0,bslot=0,gsl=0,dbase=0;
  sunroll<16>([&](auto W){
    constexpr int ww = decltype(W)::value;
    if(w==ww){
      constexpr int p = ww>>1;
      aslot = TB.col[CI].pa[p];
      bslot = TB.col[CI].pb[p];
      gsl   = TB.col[CI].gout[p];
      dbase = (ww&1)*2;
    }
  });

  const int c0 = bi*CHW, c1 = c0+CHW;
  f32x4 acc[4][2] = {};
  float rw[6][4] = {};

  auto issue = [&](int ck){
    const int b0 = (ck*KB + bl)*64 + ch;
    #pragma unroll
    for(int j=0;j<4;j++){
      const int off = b0 + j*64;
      if constexpr(LM&1u)  rw[0][j]=s1[off];
      if constexpr(LM&2u)  rw[1][j]=y1[off];
      if constexpr(LM&4u)  rw[2][j]=s2[off];
      if constexpr(LM&8u)  rw[3][j]=y2[off];
      if constexpr(LM&16u) rw[4][j]=x1[off];
      if constexpr(LM&32u) rw[5][j]=x2[off];
    }
  };
  auto stage = [&](int buf){
    u16* L = lds + buf*BUFHALF;
    sunroll<NS>([&](auto S){
      constexpr int s = decltype(S)::value;
      u16x4 o4;
      #pragma unroll
      for(int j=0;j<4;j++){
        float v = ipw<TB.col[CI].sexp[s][0]>(rw[0][j])
                * ipw<TB.col[CI].sexp[s][1]>(rw[1][j])
                * ipw<TB.col[CI].sexp[s][2]>(rw[2][j])
                * ipw<TB.col[CI].sexp[s][3]>(rw[3][j])
                * ipw<TB.col[CI].sexp[s][4]>(rw[4][j])
                * ipw<TB.col[CI].sexp[s][5]>(rw[5][j]);
        o4[j]=f2bf(v);
      }
      *(u16x4*)&L[s*4096 + wbase] = o4;
    });
  };

  // prologue: load + stage chunk c0 into buffer 0
  issue(c0);
  stage(0);
  asm volatile("s_waitcnt lgkmcnt(0)" ::: "memory");
  __builtin_amdgcn_s_barrier();
  __builtin_amdgcn_sched_barrier(0);

  for(int k=c0; k<c1; ++k){
    const int t = k - c0;
    const bool notlast = (k+1 < c1);
    if(notlast) issue(k+1);             // global prefetch (latency under MFMA)

    // MFMA on buffer t&1
    const u16* L = lds + (t&1)*BUFHALF;
    #pragma unroll
    for(int sb=0; sb<2; ++sb){
      bf16x8 Af[4];
      #pragma unroll
      for(int o2=0;o2<4;o2++) Af[o2]=readFrag(L,aslot,sb,o2,l);
      #pragma unroll
      for(int dd=0;dd<2;dd++){
        bf16x8 Bf=readFrag(L,bslot,sb,dbase+dd,l);
        #pragma unroll
        for(int o2=0;o2<4;o2++) acc[o2][dd]=mfma_(Af[o2],Bf,acc[o2][dd]);
      }
    }

    if(notlast) stage((t+1)&1);         // stage next chunk into other buffer

    // one barrier per chunk: all LDS ops (reads+writes) drained, then sync
    asm volatile("s_waitcnt lgkmcnt(0)" ::: "memory");
    __builtin_amdgcn_s_barrier();
    __builtin_amdgcn_sched_barrier(0);
  }

  // epilogue: atomic partials (C/D layout: col=lane&15, row=(lane>>4)*4+reg)
  const int r0=(l>>4)*4, cc=l&15;
  float* dst = G + gsl*4096;
  #pragma unroll
  for(int o2=0;o2<4;o2++)
    #pragma unroll
    for(int dd=0;dd<2;dd++)
      #pragma unroll
      for(int r=0;r<4;r++)
        atomicAdd(&dst[(o2*16+r0+r)*64 + (dbase+dd)*16+cc], acc[o2][dd][r]);
}

// ---- colsum block (1024 thr): all 45 colsums over 2048 rows ----
DEV void colRed(const float* __restrict__ s1,const float* __restrict__ y1,
                const float* __restrict__ s2,const float* __restrict__ y2,
                const float* __restrict__ x1,const float* __restrict__ x2,
                float* __restrict__ col, float* ldsF, int tid, int bi)
{
  const int ch=tid&63, g16=tid>>6;
  const int base = bi*2048;
  float accv[45];
  sunroll<45>([&](auto K){ accv[decltype(K)::value]=0.f; });
  for(int r=base+g16; r<base+2048; r+=16){
    const int off=r*64+ch;
    const float v0=s1[off],v1=y1[off],v2=s2[off],v3=y2[off],v4=x1[off],v5=x2[off];
    sunroll<35>([&](auto K){
      constexpr int k=decltype(K)::value;
      accv[k] += ipw<TB.am[k][0]>(v0)*ipw<TB.am[k][1]>(v1)*ipw<TB.am[k][2]>(v2)*ipw<TB.am[k][3]>(v3);
    });
    sunroll<10>([&](auto K){
      constexpr int k=decltype(K)::value;
      accv[35+k] += ipw<TB.xm[k][0]>(v4)*ipw<TB.xm[k][1]>(v5);
    });
  }
  sunroll<6>([&](auto RR){
    constexpr int rr=decltype(RR)::value;
    __syncthreads();
    sunroll<8>([&](auto Q){
      constexpr int q=decltype(Q)::value;
      if constexpr(rr*8+q < 45)
        ldsF[(q*16+g16)*64+ch]=accv[rr*8+q];
    });
    __syncthreads();
    {
      const int k=tid>>6, c=tid&63;
      const int idx=rr*8+k;
      if(k<8 && idx<45){
        float s=0.f;
        #pragma unroll
        for(int gg=0; gg<16; gg++) s+=ldsF[(k*16+gg)*64+c];
        atomicAdd(&col[idx*64+c], s);
      }
    }
  });
}

__global__ __launch_bounds__(1024, 4) void k_main(
    const float* __restrict__ x1, const float* __restrict__ s1, const float* __restrict__ y1,
    const float* __restrict__ x2, const float* __restrict__ s2, const float* __restrict__ y2,
    float* __restrict__ G, float* __restrict__ col)
{
  __shared__ u16 lds[2*BUFHALF];   // 128 KiB -> 1 block/CU
  const int tid = threadIdx.x;
  const int u = blockIdx.x >> 5;   // unit
  const int g = blockIdx.x & 31;   // window (XCD = g%8)
  if      (u==0) colGemm<0>(s1,y1,s2,y2,x1,x2,G,lds,tid,g);
  else if (u==1) colGemm<1>(s1,y1,s2,y2,x1,x2,G,lds,tid,g);
  else if (u==2) colGemm<2>(s1,y1,s2,y2,x1,x2,G,lds,tid,g);
  else if (u==3) colGemm<3>(s1,y1,s2,y2,x1,x2,G,lds,tid,g);
  else if (u==4) colGemm<4>(s1,y1,s2,y2,x1,x2,G,lds,tid,g);
  else if (u==5) colGemm<5>(s1,y1,s2,y2,x1,x2,G,lds,tid,g);
  else if (u==6) colGemm<6>(s1,y1,s2,y2,x1,x2,G,lds,tid,g);
  else           colRed(s1,y1,s2,y2,x1,x2,col,(float*)lds,tid,g);
}

__global__ __launch_bounds__(256) void k_combine(
    const float* __restrict__ G, const float* __restrict__ col,
    const float* __restrict__ w, const float* __restrict__ b, const float* __restrict__ m,
    const float* __restrict__ parw, const float* __restrict__ parb, const float* __restrict__ parm,
    float* __restrict__ out)
{
  const int n = blockIdx.x*256 + threadIdx.x;   // 0..4095
  const int o = n>>6, d = n&63;
  const float wv = w[n], mv = m[n];
  const float wp[4] = {1.f, wv, wv*wv, wv*wv*wv};
  const float mp[4] = {1.f, mv, mv*mv, mv*mv*mv};
  float aw=0.f, am=0.f;
  sunroll<120>([&](auto II){
    constexpr int i = decltype(II)::value;
    constexpr int ty = TB.wtype[i];
    constexpr int ix = TB.widx[i];
    constexpr int q  = TB.wpow[i];
    float val;
    if constexpr(ty==0) val = G[ix*4096 + n];
    else if constexpr(ty==1) val = col[ix*64 + o];
    else val = col[(35+ix)*64 + d];
    aw += parw[i] * val * wp[q];
  });
  sunroll<56>([&](auto II){
    constexpr int i = decltype(II)::value;
    constexpr int ty = TB.mtype[i];
    constexpr int ix = TB.midx[i];
    constexpr int q  = TB.mpow[i];
    float val;
    if constexpr(ty==0) val = G[ix*4096 + n];
    else if constexpr(ty==1) val = col[ix*64 + o];
    else val = col[ix*64 + d];
    am += parm[i] * val * mp[q];
  });
  aw *= INVB; am *= INVB;
  if (o==d) am += parm[56];
  out[n] = aw;
  out[4160 + n] = am;
  if (n < 64){
    const float bv = b[n];
    const float bp[4] = {1.f, bv, bv*bv, bv*bv*bv};
    float ab=0.f;
    sunroll<20>([&](auto II){
      constexpr int i = decltype(II)::value;
      constexpr int cix = TB.bcol[i];
      constexpr int q = TB.bpow[i];
      ab += parb[i] * col[cix*64 + n] * bp[q];
    });
    out[4096 + n] = ab * INVB;
  }
}

extern "C" void kernel_launch(void* const* d_in, const int* in_sizes, int n_in,
                              void* d_out, int out_size, void* d_ws, size_t ws_size,
                              hipStream_t stream)
{
  const float* x1=(const float*)d_in[0];
  const float* s1=(const float*)d_in[1];
  const float* y1=(const float*)d_in[2];
  const float* x2=(const float*)d_in[3];
  const float* s2=(const float*)d_in[4];
  const float* y2=(const float*)d_in[5];
  const float* w =(const float*)d_in[6];
  const float* b =(const float*)d_in[7];
  const float* m =(const float*)d_in[8];
  const float* parw=(const float*)d_in[9];
  const float* parb=(const float*)d_in[10];
  const float* parm=(const float*)d_in[11];

  float* G   = (float*)d_ws;
  float* col = G + NG*4096;

  hipMemsetAsync(d_ws, 0, (size_t)(NG*4096 + NCOLSUM*64)*sizeof(float), stream);
  k_main<<<GRID, 1024, 0, stream>>>(x1,s1,y1,x2,s2,y2,G,col);
  k_combine<<<16, 256, 0, stream>>>(G,col,w,b,m,parw,parb,parm,(float*)d_out);
}